// Round 4
// baseline (337.233 us; speedup 1.0000x reference)
//
#include <hip/hip_runtime.h>

// AGRU: B=2048, T=200, D=U=64, fp32. Split design v3.
// Fixes vs v2 (VGPR=80 showed weight arrays were NOT register-resident):
//  - 64 NAMED f32x2 weight vars (macro-generated, no arrays), pinned via
//    empty asm("":"+v") at load -> non-rematerializable -> must stay in VGPRs.
//  - inner product via v_pk_fma_f32 (2 fp32 FMA / instr): src0 = broadcast
//    scalar duplicated into an SGPR pair (SALU work, co-issues with VALU).
//  Per j: 1 v_readlane + 1 v_pk_fma = 2 VALU (was 3+ w/ reload overhead).

typedef float f32x2 __attribute__((ext_vector_type(2)));
typedef unsigned long long u64;

constexpr int BATCH = 2048;
constexpr int T_STEPS = 200;
constexpr int UDIM = 64;

__device__ __forceinline__ float lane_bcast(float v, int lane) {
    return __builtin_bit_cast(float, __builtin_amdgcn_readlane(__builtin_bit_cast(int, v), lane));
}

__device__ __forceinline__ float fast_sigmoid(float z) {
    return __builtin_amdgcn_rcpf(1.0f + __expf(-z));
}

__device__ __forceinline__ float fast_tanh(float z) {
    return 1.0f - 2.0f * __builtin_amdgcn_rcpf(__expf(2.0f * z) + 1.0f);
}

// ---- 64 named weight registers (pairs {A,B} per j) ----
#define DECLW(J) f32x2 w##J;
#define LOADW(J) { w##J.x = pA[(J) * UDIM + u]; w##J.y = pB[(J) * UDIM + u]; \
                   asm("" : "+v"(w##J)); }

#define ALL64(M) M(0) M(1) M(2) M(3) M(4) M(5) M(6) M(7) \
                 M(8) M(9) M(10) M(11) M(12) M(13) M(14) M(15) \
                 M(16) M(17) M(18) M(19) M(20) M(21) M(22) M(23) \
                 M(24) M(25) M(26) M(27) M(28) M(29) M(30) M(31) \
                 M(32) M(33) M(34) M(35) M(36) M(37) M(38) M(39) \
                 M(40) M(41) M(42) M(43) M(44) M(45) M(46) M(47) \
                 M(48) M(49) M(50) M(51) M(52) M(53) M(54) M(55) \
                 M(56) M(57) M(58) M(59) M(60) M(61) M(62) M(63)

// one j-step: broadcast SRC[lane J] to an SGPR pair, packed fma into ACC
#define PKSTEP(J, ACC, SRC) { \
    unsigned _b = (unsigned)__builtin_amdgcn_readlane(__builtin_bit_cast(int, SRC), J); \
    u64 _sp = ((u64)_b << 32) | (u64)_b; \
    asm("v_pk_fma_f32 %0, %1, %2, %0" : "+v"(ACC) : "s"(_sp), "v"(w##J)); \
}

#define DOT64(SRC) \
    PKSTEP(0,  accA, SRC) PKSTEP(1,  accB, SRC) PKSTEP(2,  accC, SRC) PKSTEP(3,  accD, SRC) \
    PKSTEP(4,  accA, SRC) PKSTEP(5,  accB, SRC) PKSTEP(6,  accC, SRC) PKSTEP(7,  accD, SRC) \
    PKSTEP(8,  accA, SRC) PKSTEP(9,  accB, SRC) PKSTEP(10, accC, SRC) PKSTEP(11, accD, SRC) \
    PKSTEP(12, accA, SRC) PKSTEP(13, accB, SRC) PKSTEP(14, accC, SRC) PKSTEP(15, accD, SRC) \
    PKSTEP(16, accA, SRC) PKSTEP(17, accB, SRC) PKSTEP(18, accC, SRC) PKSTEP(19, accD, SRC) \
    PKSTEP(20, accA, SRC) PKSTEP(21, accB, SRC) PKSTEP(22, accC, SRC) PKSTEP(23, accD, SRC) \
    PKSTEP(24, accA, SRC) PKSTEP(25, accB, SRC) PKSTEP(26, accC, SRC) PKSTEP(27, accD, SRC) \
    PKSTEP(28, accA, SRC) PKSTEP(29, accB, SRC) PKSTEP(30, accC, SRC) PKSTEP(31, accD, SRC) \
    PKSTEP(32, accA, SRC) PKSTEP(33, accB, SRC) PKSTEP(34, accC, SRC) PKSTEP(35, accD, SRC) \
    PKSTEP(36, accA, SRC) PKSTEP(37, accB, SRC) PKSTEP(38, accC, SRC) PKSTEP(39, accD, SRC) \
    PKSTEP(40, accA, SRC) PKSTEP(41, accB, SRC) PKSTEP(42, accC, SRC) PKSTEP(43, accD, SRC) \
    PKSTEP(44, accA, SRC) PKSTEP(45, accB, SRC) PKSTEP(46, accC, SRC) PKSTEP(47, accD, SRC) \
    PKSTEP(48, accA, SRC) PKSTEP(49, accB, SRC) PKSTEP(50, accC, SRC) PKSTEP(51, accD, SRC) \
    PKSTEP(52, accA, SRC) PKSTEP(53, accB, SRC) PKSTEP(54, accC, SRC) PKSTEP(55, accD, SRC) \
    PKSTEP(56, accA, SRC) PKSTEP(57, accB, SRC) PKSTEP(58, accC, SRC) PKSTEP(59, accD, SRC) \
    PKSTEP(60, accA, SRC) PKSTEP(61, accB, SRC) PKSTEP(62, accC, SRC) PKSTEP(63, accD, SRC)

// ---------------- Kernel 1: input projections ----------------
// 1024 blocks x 256 = 4096 waves; 409600 rows = 4096 * 25 groups * 4 rows.
__global__ __launch_bounds__(256, 3) void proj_kernel(
    const float* __restrict__ x,     // [B*T,64]
    const float* __restrict__ w_ir,  // [64,64]
    const float* __restrict__ w_ih,  // [64,64]
    const float* __restrict__ b_ir,
    const float* __restrict__ b_hr,
    const float* __restrict__ b_ih,
    f32x2* __restrict__ pre)         // [B*T,64] of {pre_r, pre_h}
{
    const int u = threadIdx.x & 63;
    const float* pA = w_ir;
    const float* pB = w_ih;

    ALL64(DECLW)
    ALL64(LOADW)

    const float br = b_ir[u] + b_hr[u];
    const float bh = b_ih[u];

    const int nwaves = (int)((gridDim.x * blockDim.x) >> 6);        // 4096
    const int wid = (int)((blockIdx.x * blockDim.x + threadIdx.x) >> 6);

    const int ngroups = (BATCH * T_STEPS) / 4;                       // 102400
    const float* xp = x + u;

    long r = (long)wid * 4;
    float xa = xp[(r + 0) * UDIM];
    float xb = xp[(r + 1) * UDIM];
    float xc = xp[(r + 2) * UDIM];
    float xd = xp[(r + 3) * UDIM];

    for (int g = wid; g < ngroups; g += nwaves) {
        const int gn = (g + nwaves < ngroups) ? (g + nwaves) : g;
        const long rn = (long)gn * 4;
        float na = xp[(rn + 0) * UDIM];
        float nb = xp[(rn + 1) * UDIM];
        float nc = xp[(rn + 2) * UDIM];
        float nd = xp[(rn + 3) * UDIM];

        f32x2* po = pre + (long)g * 4 * UDIM + u;

        {   f32x2 accA = {br, bh}, accB = {0.f, 0.f}, accC = {0.f, 0.f}, accD = {0.f, 0.f};
            DOT64(xa)
            po[0 * UDIM] = (accA + accB) + (accC + accD); }
        {   f32x2 accA = {br, bh}, accB = {0.f, 0.f}, accC = {0.f, 0.f}, accD = {0.f, 0.f};
            DOT64(xb)
            po[1 * UDIM] = (accA + accB) + (accC + accD); }
        {   f32x2 accA = {br, bh}, accB = {0.f, 0.f}, accC = {0.f, 0.f}, accD = {0.f, 0.f};
            DOT64(xc)
            po[2 * UDIM] = (accA + accB) + (accC + accD); }
        {   f32x2 accA = {br, bh}, accB = {0.f, 0.f}, accC = {0.f, 0.f}, accD = {0.f, 0.f};
            DOT64(xd)
            po[3 * UDIM] = (accA + accB) + (accC + accD); }

        xa = na; xb = nb; xc = nc; xd = nd;
    }
}

// ---------------- Kernel 2: recurrence ----------------
// 512 blocks x 256 = 2048 waves, 1 batch row per wave (8 waves/CU, 2/SIMD).
__global__ __launch_bounds__(256, 2) void rec_kernel(
    const f32x2* __restrict__ pre,   // [B*T,64] {pre_r, pre_h}
    const float* __restrict__ att,   // [B,T]
    const float* __restrict__ h0,    // [B,64]
    const float* __restrict__ w_hr,  // [64,64]
    const float* __restrict__ w_hh,  // [64,64]
    const float* __restrict__ b_hh,  // [64]
    float* __restrict__ out)         // [B,T,64]
{
    const int u = threadIdx.x & 63;
    const int row = (int)((blockIdx.x * blockDim.x + threadIdx.x) >> 6);
    const float* pA = w_hr;
    const float* pB = w_hh;

    ALL64(DECLW)
    ALL64(LOADW)

    const float bg = b_hh[u];

    float h = h0[(long)row * UDIM + u];

    const f32x2* pp = pre + (long)row * T_STEPS * UDIM + u;
    const float* ap = att + (long)row * T_STEPS;
    float*       op = out + (long)row * T_STEPS * UDIM + u;

    // 3-deep prefetch pipeline (static shift registers)
    f32x2 pv0 = pp[0 * UDIM];
    f32x2 pv1 = pp[1 * UDIM];
    f32x2 pv2 = pp[2 * UDIM];
    float av0 = ap[0];
    float av1 = ap[1];
    float av2 = ap[2];

    for (int t = 0; t < T_STEPS; ++t) {
        const int tf = (t + 3 < T_STEPS) ? (t + 3) : (T_STEPS - 1);
        f32x2 pvn = pp[(long)tf * UDIM];
        float avn = ap[tf];

        f32x2 accA = {0.f, 0.f}, accB = {0.f, 0.f}, accC = {0.f, 0.f}, accD = {0.f, 0.f};
        DOT64(h)
        f32x2 s = (accA + accB) + (accC + accD);   // {h@w_hr, h@w_hh}

        const float r  = fast_sigmoid(pv0.x + s.x);
        const float hc = fast_tanh(fmaf(r, s.y + bg, pv0.y));
        h = fmaf(av0, hc - h, h);                  // (1-a)h + a*hc

        op[(long)t * UDIM] = h;

        pv0 = pv1; pv1 = pv2; pv2 = pvn;
        av0 = av1; av1 = av2; av2 = avn;
    }
}

// ---------------- Fallback: fused kernel (small ws) ----------------
__global__ __launch_bounds__(256) void agru_fused_kernel(
    const float* __restrict__ x, const float* __restrict__ att,
    const float* __restrict__ h0,
    const float* __restrict__ w_ir, const float* __restrict__ w_hr,
    const float* __restrict__ b_ir, const float* __restrict__ b_hr,
    const float* __restrict__ w_ih, const float* __restrict__ w_hh,
    const float* __restrict__ b_ih, const float* __restrict__ b_hh,
    float* __restrict__ out)
{
    __shared__ float lds[4 * UDIM * UDIM];
    const int tid = threadIdx.x;
    #pragma unroll
    for (int i = 0; i < 16; ++i) {
        int e = tid + 256 * i;
        lds[e] = w_ir[e]; lds[4096 + e] = w_ih[e];
        lds[8192 + e] = w_hr[e]; lds[12288 + e] = w_hh[e];
    }
    __syncthreads();

    const int wave = tid >> 6;
    const int u = tid & 63;
    const int r0 = blockIdx.x * 8 + wave * 2;
    const int r1 = r0 + 1;

    float h_0 = h0[r0 * UDIM + u];
    float h_1 = h0[r1 * UDIM + u];
    const float bR = b_ir[u] + b_hr[u];
    const float bH = b_ih[u];
    const float bG = b_hh[u];

    const float* xp0 = x + (long)r0 * T_STEPS * UDIM + u;
    const float* xp1 = x + (long)r1 * T_STEPS * UDIM + u;
    const float* ap0 = att + (long)r0 * T_STEPS;
    const float* ap1 = att + (long)r1 * T_STEPS;
    float* op0 = out + (long)r0 * T_STEPS * UDIM + u;
    float* op1 = out + (long)r1 * T_STEPS * UDIM + u;

    float xv0 = xp0[0], xv1 = xp1[0], a0 = ap0[0], a1 = ap1[0];

    for (int t = 0; t < T_STEPS; ++t) {
        const int tn = (t + 1 < T_STEPS) ? (t + 1) : t;
        float nxv0 = xp0[(long)tn * UDIM], nxv1 = xp1[(long)tn * UDIM];
        float na0 = ap0[tn], na1 = ap1[tn];

        float accR0 = bR, accR1 = bR, accH0 = bH, accH1 = bH, accG0 = bG, accG1 = bG;
        #pragma unroll
        for (int j = 0; j < 64; ++j) {
            const float wir = lds[j * 64 + u];
            const float wih = lds[4096 + j * 64 + u];
            const float whr = lds[8192 + j * 64 + u];
            const float whh = lds[12288 + j * 64 + u];
            const float xj0 = lane_bcast(xv0, j);
            const float xj1 = lane_bcast(xv1, j);
            const float hj0 = lane_bcast(h_0, j);
            const float hj1 = lane_bcast(h_1, j);
            accR0 = fmaf(xj0, wir, accR0); accR0 = fmaf(hj0, whr, accR0);
            accH0 = fmaf(xj0, wih, accH0); accG0 = fmaf(hj0, whh, accG0);
            accR1 = fmaf(xj1, wir, accR1); accR1 = fmaf(hj1, whr, accR1);
            accH1 = fmaf(xj1, wih, accH1); accG1 = fmaf(hj1, whh, accG1);
        }
        const float r0g = fast_sigmoid(accR0);
        const float r1g = fast_sigmoid(accR1);
        const float hc0 = fast_tanh(fmaf(r0g, accG0, accH0));
        const float hc1 = fast_tanh(fmaf(r1g, accG1, accH1));
        h_0 = fmaf(a0, hc0 - h_0, h_0);
        h_1 = fmaf(a1, hc1 - h_1, h_1);
        op0[(long)t * UDIM] = h_0;
        op1[(long)t * UDIM] = h_1;
        xv0 = nxv0; xv1 = nxv1; a0 = na0; a1 = na1;
    }
}

extern "C" void kernel_launch(void* const* d_in, const int* in_sizes, int n_in,
                              void* d_out, int out_size, void* d_ws, size_t ws_size,
                              hipStream_t stream) {
    (void)in_sizes; (void)n_in; (void)out_size;

    const float* x    = (const float*)d_in[0];
    const float* att  = (const float*)d_in[1];
    const float* h0   = (const float*)d_in[2];
    const float* w_ir = (const float*)d_in[3];
    const float* w_hr = (const float*)d_in[4];
    const float* b_ir = (const float*)d_in[5];
    const float* b_hr = (const float*)d_in[6];
    const float* w_ih = (const float*)d_in[7];
    const float* w_hh = (const float*)d_in[8];
    const float* b_ih = (const float*)d_in[9];
    const float* b_hh = (const float*)d_in[10];
    float* out = (float*)d_out;

    const size_t pre_bytes = (size_t)BATCH * T_STEPS * UDIM * sizeof(f32x2); // 210 MB

    if (ws_size >= pre_bytes) {
        f32x2* pre = (f32x2*)d_ws;
        proj_kernel<<<dim3(1024), dim3(256), 0, stream>>>(
            x, w_ir, w_ih, b_ir, b_hr, b_ih, pre);
        rec_kernel<<<dim3(512), dim3(256), 0, stream>>>(
            pre, att, h0, w_hr, w_hh, b_hh, out);
    } else {
        agru_fused_kernel<<<dim3(256), dim3(256), 0, stream>>>(
            x, att, h0, w_ir, w_hr, b_ir, b_hr, w_ih, w_hh, b_ih, b_hh, out);
    }
}

// Round 5
// 294.088 us; speedup vs baseline: 1.1467x; 1.1467x over previous
//
#include <hip/hip_runtime.h>

// AGRU: B=2048, T=200, D=U=64, fp32. Split design v4.
// Root cause found in v2/v3: weight "register arrays" were never resident
// (VGPR_Count=80) -- compiler sank the loads into the loop and re-fetched
// 512B of weights from L2 per row-group, serializing on vmcnt.
// Fix: VOLATILE asm pin of all 64 named f32x2 weight vars INSIDE the loop.
// The values are inputs+outputs of a volatile asm each iteration, so all
// 128 VGPRs must be live across the back-edge: loads stay in the preamble,
// rematerialization/sinking is impossible. Compute is plain fmaf
// (readlane -> v_fmac sgpr-src); no hand-rolled pk_fma chains.

typedef float f32x2 __attribute__((ext_vector_type(2)));

constexpr int BATCH = 2048;
constexpr int T_STEPS = 200;
constexpr int UDIM = 64;

__device__ __forceinline__ float lane_bcast(float v, int lane) {
    return __builtin_bit_cast(float, __builtin_amdgcn_readlane(__builtin_bit_cast(int, v), lane));
}

__device__ __forceinline__ float fast_sigmoid(float z) {
    return __builtin_amdgcn_rcpf(1.0f + __expf(-z));
}

__device__ __forceinline__ float fast_tanh(float z) {
    return 1.0f - 2.0f * __builtin_amdgcn_rcpf(__expf(2.0f * z) + 1.0f);
}

// ---- 64 named weight registers (pairs {A,B} per j) ----
#define DECLW(J) f32x2 w##J;
#define LOADW(J) { w##J.x = pA[(J) * UDIM + u]; w##J.y = pB[(J) * UDIM + u]; }

#define ALL64(M) M(0) M(1) M(2) M(3) M(4) M(5) M(6) M(7) \
                 M(8) M(9) M(10) M(11) M(12) M(13) M(14) M(15) \
                 M(16) M(17) M(18) M(19) M(20) M(21) M(22) M(23) \
                 M(24) M(25) M(26) M(27) M(28) M(29) M(30) M(31) \
                 M(32) M(33) M(34) M(35) M(36) M(37) M(38) M(39) \
                 M(40) M(41) M(42) M(43) M(44) M(45) M(46) M(47) \
                 M(48) M(49) M(50) M(51) M(52) M(53) M(54) M(55) \
                 M(56) M(57) M(58) M(59) M(60) M(61) M(62) M(63)

// Volatile in-loop pin: forces all weights simultaneously VGPR-resident.
#define PIN8(A,B,C,D,E,F,G,H) \
    asm volatile("" : "+v"(w##A), "+v"(w##B), "+v"(w##C), "+v"(w##D), \
                      "+v"(w##E), "+v"(w##F), "+v"(w##G), "+v"(w##H));
#define PIN_LIVE \
    PIN8(0,1,2,3,4,5,6,7)       PIN8(8,9,10,11,12,13,14,15) \
    PIN8(16,17,18,19,20,21,22,23) PIN8(24,25,26,27,28,29,30,31) \
    PIN8(32,33,34,35,36,37,38,39) PIN8(40,41,42,43,44,45,46,47) \
    PIN8(48,49,50,51,52,53,54,55) PIN8(56,57,58,59,60,61,62,63)

// one j-step: broadcast SRC[lane J], two fmaf into packed acc
#define JSTEP(J, ACC, SRC) { \
    const float _s = lane_bcast(SRC, J); \
    ACC.x = fmaf(_s, w##J.x, ACC.x); \
    ACC.y = fmaf(_s, w##J.y, ACC.y); \
}

#define DOT64(SRC) \
    JSTEP(0,  accA, SRC) JSTEP(1,  accB, SRC) JSTEP(2,  accC, SRC) JSTEP(3,  accD, SRC) \
    JSTEP(4,  accA, SRC) JSTEP(5,  accB, SRC) JSTEP(6,  accC, SRC) JSTEP(7,  accD, SRC) \
    JSTEP(8,  accA, SRC) JSTEP(9,  accB, SRC) JSTEP(10, accC, SRC) JSTEP(11, accD, SRC) \
    JSTEP(12, accA, SRC) JSTEP(13, accB, SRC) JSTEP(14, accC, SRC) JSTEP(15, accD, SRC) \
    JSTEP(16, accA, SRC) JSTEP(17, accB, SRC) JSTEP(18, accC, SRC) JSTEP(19, accD, SRC) \
    JSTEP(20, accA, SRC) JSTEP(21, accB, SRC) JSTEP(22, accC, SRC) JSTEP(23, accD, SRC) \
    JSTEP(24, accA, SRC) JSTEP(25, accB, SRC) JSTEP(26, accC, SRC) JSTEP(27, accD, SRC) \
    JSTEP(28, accA, SRC) JSTEP(29, accB, SRC) JSTEP(30, accC, SRC) JSTEP(31, accD, SRC) \
    JSTEP(32, accA, SRC) JSTEP(33, accB, SRC) JSTEP(34, accC, SRC) JSTEP(35, accD, SRC) \
    JSTEP(36, accA, SRC) JSTEP(37, accB, SRC) JSTEP(38, accC, SRC) JSTEP(39, accD, SRC) \
    JSTEP(40, accA, SRC) JSTEP(41, accB, SRC) JSTEP(42, accC, SRC) JSTEP(43, accD, SRC) \
    JSTEP(44, accA, SRC) JSTEP(45, accB, SRC) JSTEP(46, accC, SRC) JSTEP(47, accD, SRC) \
    JSTEP(48, accA, SRC) JSTEP(49, accB, SRC) JSTEP(50, accC, SRC) JSTEP(51, accD, SRC) \
    JSTEP(52, accA, SRC) JSTEP(53, accB, SRC) JSTEP(54, accC, SRC) JSTEP(55, accD, SRC) \
    JSTEP(56, accA, SRC) JSTEP(57, accB, SRC) JSTEP(58, accC, SRC) JSTEP(59, accD, SRC) \
    JSTEP(60, accA, SRC) JSTEP(61, accB, SRC) JSTEP(62, accC, SRC) JSTEP(63, accD, SRC)

// ---------------- Kernel 1: input projections ----------------
// 1024 blocks x 256 = 4096 waves; 409600 rows = 4096 waves * 25 groups * 4.
__global__ __launch_bounds__(256, 3) void proj_kernel(
    const float* __restrict__ x,     // [B*T,64]
    const float* __restrict__ w_ir,  // [64,64]
    const float* __restrict__ w_ih,  // [64,64]
    const float* __restrict__ b_ir,
    const float* __restrict__ b_hr,
    const float* __restrict__ b_ih,
    f32x2* __restrict__ pre)         // [B*T,64] of {pre_r, pre_h}
{
    const int u = threadIdx.x & 63;
    const float* pA = w_ir;
    const float* pB = w_ih;

    ALL64(DECLW)
    ALL64(LOADW)

    const float br = b_ir[u] + b_hr[u];
    const float bh = b_ih[u];

    const int nwaves = (int)((gridDim.x * blockDim.x) >> 6);        // 4096
    const int wid = (int)((blockIdx.x * blockDim.x + threadIdx.x) >> 6);

    const int ngroups = (BATCH * T_STEPS) / 4;                       // 102400
    const float* xp = x + u;

    long r = (long)wid * 4;
    float xa = xp[(r + 0) * UDIM];
    float xb = xp[(r + 1) * UDIM];
    float xc = xp[(r + 2) * UDIM];
    float xd = xp[(r + 3) * UDIM];

    for (int g = wid; g < ngroups; g += nwaves) {
        PIN_LIVE   // weights must all be in VGPRs here, every iteration

        const int gn = (g + nwaves < ngroups) ? (g + nwaves) : g;
        const long rn = (long)gn * 4;
        float na = xp[(rn + 0) * UDIM];
        float nb = xp[(rn + 1) * UDIM];
        float nc = xp[(rn + 2) * UDIM];
        float nd = xp[(rn + 3) * UDIM];

        f32x2* po = pre + (long)g * 4 * UDIM + u;

        {   f32x2 accA = {br, bh}, accB = {0.f, 0.f}, accC = {0.f, 0.f}, accD = {0.f, 0.f};
            DOT64(xa)
            po[0 * UDIM] = (accA + accB) + (accC + accD); }
        {   f32x2 accA = {br, bh}, accB = {0.f, 0.f}, accC = {0.f, 0.f}, accD = {0.f, 0.f};
            DOT64(xb)
            po[1 * UDIM] = (accA + accB) + (accC + accD); }
        {   f32x2 accA = {br, bh}, accB = {0.f, 0.f}, accC = {0.f, 0.f}, accD = {0.f, 0.f};
            DOT64(xc)
            po[2 * UDIM] = (accA + accB) + (accC + accD); }
        {   f32x2 accA = {br, bh}, accB = {0.f, 0.f}, accC = {0.f, 0.f}, accD = {0.f, 0.f};
            DOT64(xd)
            po[3 * UDIM] = (accA + accB) + (accC + accD); }

        xa = na; xb = nb; xc = nc; xd = nd;
    }
}

// ---------------- Kernel 2: recurrence ----------------
// 512 blocks x 256 = 2048 waves, 1 batch row per wave.
__global__ __launch_bounds__(256, 2) void rec_kernel(
    const f32x2* __restrict__ pre,   // [B*T,64] {pre_r, pre_h}
    const float* __restrict__ att,   // [B,T]
    const float* __restrict__ h0,    // [B,64]
    const float* __restrict__ w_hr,  // [64,64]
    const float* __restrict__ w_hh,  // [64,64]
    const float* __restrict__ b_hh,  // [64]
    float* __restrict__ out)         // [B,T,64]
{
    const int u = threadIdx.x & 63;
    const int row = (int)((blockIdx.x * blockDim.x + threadIdx.x) >> 6);
    const float* pA = w_hr;
    const float* pB = w_hh;

    ALL64(DECLW)
    ALL64(LOADW)

    const float bg = b_hh[u];

    float h = h0[(long)row * UDIM + u];

    const f32x2* pp = pre + (long)row * T_STEPS * UDIM + u;
    const float* ap = att + (long)row * T_STEPS;
    float*       op = out + (long)row * T_STEPS * UDIM + u;

    // 3-deep prefetch pipeline (static shift registers)
    f32x2 pv0 = pp[0 * UDIM];
    f32x2 pv1 = pp[1 * UDIM];
    f32x2 pv2 = pp[2 * UDIM];
    float av0 = ap[0];
    float av1 = ap[1];
    float av2 = ap[2];

    for (int t = 0; t < T_STEPS; ++t) {
        PIN_LIVE   // weights must all be in VGPRs here, every timestep

        const int tf = (t + 3 < T_STEPS) ? (t + 3) : (T_STEPS - 1);
        f32x2 pvn = pp[(long)tf * UDIM];
        float avn = ap[tf];

        f32x2 accA = {0.f, 0.f}, accB = {0.f, 0.f}, accC = {0.f, 0.f}, accD = {0.f, 0.f};
        DOT64(h)
        f32x2 s = (accA + accB) + (accC + accD);   // {h@w_hr, h@w_hh}

        const float r  = fast_sigmoid(pv0.x + s.x);
        const float hc = fast_tanh(fmaf(r, s.y + bg, pv0.y));
        h = fmaf(av0, hc - h, h);                  // (1-a)h + a*hc

        op[(long)t * UDIM] = h;

        pv0 = pv1; pv1 = pv2; pv2 = pvn;
        av0 = av1; av1 = av2; av2 = avn;
    }
}

// ---------------- Fallback: fused kernel (small ws) ----------------
__global__ __launch_bounds__(256) void agru_fused_kernel(
    const float* __restrict__ x, const float* __restrict__ att,
    const float* __restrict__ h0,
    const float* __restrict__ w_ir, const float* __restrict__ w_hr,
    const float* __restrict__ b_ir, const float* __restrict__ b_hr,
    const float* __restrict__ w_ih, const float* __restrict__ w_hh,
    const float* __restrict__ b_ih, const float* __restrict__ b_hh,
    float* __restrict__ out)
{
    __shared__ float lds[4 * UDIM * UDIM];
    const int tid = threadIdx.x;
    #pragma unroll
    for (int i = 0; i < 16; ++i) {
        int e = tid + 256 * i;
        lds[e] = w_ir[e]; lds[4096 + e] = w_ih[e];
        lds[8192 + e] = w_hr[e]; lds[12288 + e] = w_hh[e];
    }
    __syncthreads();

    const int wave = tid >> 6;
    const int u = tid & 63;
    const int r0 = blockIdx.x * 8 + wave * 2;
    const int r1 = r0 + 1;

    float h_0 = h0[r0 * UDIM + u];
    float h_1 = h0[r1 * UDIM + u];
    const float bR = b_ir[u] + b_hr[u];
    const float bH = b_ih[u];
    const float bG = b_hh[u];

    const float* xp0 = x + (long)r0 * T_STEPS * UDIM + u;
    const float* xp1 = x + (long)r1 * T_STEPS * UDIM + u;
    const float* ap0 = att + (long)r0 * T_STEPS;
    const float* ap1 = att + (long)r1 * T_STEPS;
    float* op0 = out + (long)r0 * T_STEPS * UDIM + u;
    float* op1 = out + (long)r1 * T_STEPS * UDIM + u;

    float xv0 = xp0[0], xv1 = xp1[0], a0 = ap0[0], a1 = ap1[0];

    for (int t = 0; t < T_STEPS; ++t) {
        const int tn = (t + 1 < T_STEPS) ? (t + 1) : t;
        float nxv0 = xp0[(long)tn * UDIM], nxv1 = xp1[(long)tn * UDIM];
        float na0 = ap0[tn], na1 = ap1[tn];

        float accR0 = bR, accR1 = bR, accH0 = bH, accH1 = bH, accG0 = bG, accG1 = bG;
        #pragma unroll
        for (int j = 0; j < 64; ++j) {
            const float wir = lds[j * 64 + u];
            const float wih = lds[4096 + j * 64 + u];
            const float whr = lds[8192 + j * 64 + u];
            const float whh = lds[12288 + j * 64 + u];
            const float xj0 = lane_bcast(xv0, j);
            const float xj1 = lane_bcast(xv1, j);
            const float hj0 = lane_bcast(h_0, j);
            const float hj1 = lane_bcast(h_1, j);
            accR0 = fmaf(xj0, wir, accR0); accR0 = fmaf(hj0, whr, accR0);
            accH0 = fmaf(xj0, wih, accH0); accG0 = fmaf(hj0, whh, accG0);
            accR1 = fmaf(xj1, wir, accR1); accR1 = fmaf(hj1, whr, accR1);
            accH1 = fmaf(xj1, wih, accH1); accG1 = fmaf(hj1, whh, accG1);
        }
        const float r0g = fast_sigmoid(accR0);
        const float r1g = fast_sigmoid(accR1);
        const float hc0 = fast_tanh(fmaf(r0g, accG0, accH0));
        const float hc1 = fast_tanh(fmaf(r1g, accG1, accH1));
        h_0 = fmaf(a0, hc0 - h_0, h_0);
        h_1 = fmaf(a1, hc1 - h_1, h_1);
        op0[(long)t * UDIM] = h_0;
        op1[(long)t * UDIM] = h_1;
        xv0 = nxv0; xv1 = nxv1; a0 = na0; a1 = na1;
    }
}

extern "C" void kernel_launch(void* const* d_in, const int* in_sizes, int n_in,
                              void* d_out, int out_size, void* d_ws, size_t ws_size,
                              hipStream_t stream) {
    (void)in_sizes; (void)n_in; (void)out_size;

    const float* x    = (const float*)d_in[0];
    const float* att  = (const float*)d_in[1];
    const float* h0   = (const float*)d_in[2];
    const float* w_ir = (const float*)d_in[3];
    const float* w_hr = (const float*)d_in[4];
    const float* b_ir = (const float*)d_in[5];
    const float* b_hr = (const float*)d_in[6];
    const float* w_ih = (const float*)d_in[7];
    const float* w_hh = (const float*)d_in[8];
    const float* b_ih = (const float*)d_in[9];
    const float* b_hh = (const float*)d_in[10];
    float* out = (float*)d_out;

    const size_t pre_bytes = (size_t)BATCH * T_STEPS * UDIM * sizeof(f32x2); // 210 MB

    if (ws_size >= pre_bytes) {
        f32x2* pre = (f32x2*)d_ws;
        proj_kernel<<<dim3(1024), dim3(256), 0, stream>>>(
            x, w_ir, w_ih, b_ir, b_hr, b_ih, pre);
        rec_kernel<<<dim3(512), dim3(256), 0, stream>>>(
            pre, att, h0, w_hr, w_hh, b_hh, out);
    } else {
        agru_fused_kernel<<<dim3(256), dim3(256), 0, stream>>>(
            x, att, h0, w_ir, w_hr, b_ir, b_hr, w_ih, w_hh, b_ih, b_hh, out);
    }
}

// Round 6
// 277.454 us; speedup vs baseline: 1.2155x; 1.0600x over previous
//
#include <hip/hip_runtime.h>

// AGRU: B=2048, T=200, D=U=64, fp32. Split design v5.
// v2-v4 post-mortems: weight arrays were never arch-VGPR-resident
// (VGPR_Count stuck at 80) -- the gfx950 allocator PARKS cold values in
// AGPRs (v_accvgpr_read/write shuttles) to chase a higher occupancy target,
// costing ~3x VALU per weight use. Fix: declare EXACT occupancy
// amdgpu_waves_per_eu(2,2) so there is no occupancy payoff for freeing
// VGPRs; 128 weight floats then stay in arch VGPRs. Grids sized to exactly
// 2 waves/SIMD. In-loop pins kept (zero-cost once resident).

typedef float f32x2 __attribute__((ext_vector_type(2)));

constexpr int BATCH = 2048;
constexpr int T_STEPS = 200;
constexpr int UDIM = 64;

__device__ __forceinline__ float lane_bcast(float v, int lane) {
    return __builtin_bit_cast(float, __builtin_amdgcn_readlane(__builtin_bit_cast(int, v), lane));
}

__device__ __forceinline__ float fast_sigmoid(float z) {
    return __builtin_amdgcn_rcpf(1.0f + __expf(-z));
}

__device__ __forceinline__ float fast_tanh(float z) {
    return 1.0f - 2.0f * __builtin_amdgcn_rcpf(__expf(2.0f * z) + 1.0f);
}

// ---- 64 named weight registers (pairs {A,B} per j) ----
#define DECLW(J) f32x2 w##J;
#define LOADW(J) { w##J.x = pA[(J) * UDIM + u]; w##J.y = pB[(J) * UDIM + u]; }

#define ALL64(M) M(0) M(1) M(2) M(3) M(4) M(5) M(6) M(7) \
                 M(8) M(9) M(10) M(11) M(12) M(13) M(14) M(15) \
                 M(16) M(17) M(18) M(19) M(20) M(21) M(22) M(23) \
                 M(24) M(25) M(26) M(27) M(28) M(29) M(30) M(31) \
                 M(32) M(33) M(34) M(35) M(36) M(37) M(38) M(39) \
                 M(40) M(41) M(42) M(43) M(44) M(45) M(46) M(47) \
                 M(48) M(49) M(50) M(51) M(52) M(53) M(54) M(55) \
                 M(56) M(57) M(58) M(59) M(60) M(61) M(62) M(63)

#define PIN8(A,B,C,D,E,F,G,H) \
    asm volatile("" : "+v"(w##A), "+v"(w##B), "+v"(w##C), "+v"(w##D), \
                      "+v"(w##E), "+v"(w##F), "+v"(w##G), "+v"(w##H));
#define PIN_LIVE \
    PIN8(0,1,2,3,4,5,6,7)         PIN8(8,9,10,11,12,13,14,15) \
    PIN8(16,17,18,19,20,21,22,23) PIN8(24,25,26,27,28,29,30,31) \
    PIN8(32,33,34,35,36,37,38,39) PIN8(40,41,42,43,44,45,46,47) \
    PIN8(48,49,50,51,52,53,54,55) PIN8(56,57,58,59,60,61,62,63)

// one j-step: broadcast SRC[lane J], packed mul-add into ACC
// (ffp-contract folds to v_pk_fma_f32 or 2x v_fmac with sgpr src)
#define JSTEP(J, ACC, SRC) { \
    const float _s = lane_bcast(SRC, J); \
    f32x2 _sv; _sv.x = _s; _sv.y = _s; \
    ACC += _sv * w##J; \
}

#define DOT64(SRC) \
    JSTEP(0,  accA, SRC) JSTEP(1,  accB, SRC) JSTEP(2,  accC, SRC) JSTEP(3,  accD, SRC) \
    JSTEP(4,  accA, SRC) JSTEP(5,  accB, SRC) JSTEP(6,  accC, SRC) JSTEP(7,  accD, SRC) \
    JSTEP(8,  accA, SRC) JSTEP(9,  accB, SRC) JSTEP(10, accC, SRC) JSTEP(11, accD, SRC) \
    JSTEP(12, accA, SRC) JSTEP(13, accB, SRC) JSTEP(14, accC, SRC) JSTEP(15, accD, SRC) \
    JSTEP(16, accA, SRC) JSTEP(17, accB, SRC) JSTEP(18, accC, SRC) JSTEP(19, accD, SRC) \
    JSTEP(20, accA, SRC) JSTEP(21, accB, SRC) JSTEP(22, accC, SRC) JSTEP(23, accD, SRC) \
    JSTEP(24, accA, SRC) JSTEP(25, accB, SRC) JSTEP(26, accC, SRC) JSTEP(27, accD, SRC) \
    JSTEP(28, accA, SRC) JSTEP(29, accB, SRC) JSTEP(30, accC, SRC) JSTEP(31, accD, SRC) \
    JSTEP(32, accA, SRC) JSTEP(33, accB, SRC) JSTEP(34, accC, SRC) JSTEP(35, accD, SRC) \
    JSTEP(36, accA, SRC) JSTEP(37, accB, SRC) JSTEP(38, accC, SRC) JSTEP(39, accD, SRC) \
    JSTEP(40, accA, SRC) JSTEP(41, accB, SRC) JSTEP(42, accC, SRC) JSTEP(43, accD, SRC) \
    JSTEP(44, accA, SRC) JSTEP(45, accB, SRC) JSTEP(46, accC, SRC) JSTEP(47, accD, SRC) \
    JSTEP(48, accA, SRC) JSTEP(49, accB, SRC) JSTEP(50, accC, SRC) JSTEP(51, accD, SRC) \
    JSTEP(52, accA, SRC) JSTEP(53, accB, SRC) JSTEP(54, accC, SRC) JSTEP(55, accD, SRC) \
    JSTEP(56, accA, SRC) JSTEP(57, accB, SRC) JSTEP(58, accC, SRC) JSTEP(59, accD, SRC) \
    JSTEP(60, accA, SRC) JSTEP(61, accB, SRC) JSTEP(62, accC, SRC) JSTEP(63, accD, SRC)

// ---------------- Kernel 1: input projections ----------------
// 1024 blocks x 256 thr; 409600 rows = 4096 waves * 25 groups * 4 rows.
__global__ __launch_bounds__(256)
__attribute__((amdgpu_waves_per_eu(2, 2)))
void proj_kernel(
    const float* __restrict__ x,     // [B*T,64]
    const float* __restrict__ w_ir,  // [64,64]
    const float* __restrict__ w_ih,  // [64,64]
    const float* __restrict__ b_ir,
    const float* __restrict__ b_hr,
    const float* __restrict__ b_ih,
    f32x2* __restrict__ pre)         // [B*T,64] of {pre_r, pre_h}
{
    const int u = threadIdx.x & 63;
    const float* pA = w_ir;
    const float* pB = w_ih;

    ALL64(DECLW)
    ALL64(LOADW)

    const float br = b_ir[u] + b_hr[u];
    const float bh = b_ih[u];

    const int nwaves = (int)((gridDim.x * blockDim.x) >> 6);        // 4096
    const int wid = (int)((blockIdx.x * blockDim.x + threadIdx.x) >> 6);

    const int ngroups = (BATCH * T_STEPS) / 4;                       // 102400
    const float* xp = x + u;

    long r = (long)wid * 4;
    float xa = xp[(r + 0) * UDIM];
    float xb = xp[(r + 1) * UDIM];
    float xc = xp[(r + 2) * UDIM];
    float xd = xp[(r + 3) * UDIM];

    for (int g = wid; g < ngroups; g += nwaves) {
        PIN_LIVE   // zero-cost when resident; forbids sinking/remat

        const int gn = (g + nwaves < ngroups) ? (g + nwaves) : g;
        const long rn = (long)gn * 4;
        float na = xp[(rn + 0) * UDIM];
        float nb = xp[(rn + 1) * UDIM];
        float nc = xp[(rn + 2) * UDIM];
        float nd = xp[(rn + 3) * UDIM];

        f32x2* po = pre + (long)g * 4 * UDIM + u;

        {   f32x2 accA = {br, bh}, accB = {0.f, 0.f}, accC = {0.f, 0.f}, accD = {0.f, 0.f};
            DOT64(xa)
            po[0 * UDIM] = (accA + accB) + (accC + accD); }
        {   f32x2 accA = {br, bh}, accB = {0.f, 0.f}, accC = {0.f, 0.f}, accD = {0.f, 0.f};
            DOT64(xb)
            po[1 * UDIM] = (accA + accB) + (accC + accD); }
        {   f32x2 accA = {br, bh}, accB = {0.f, 0.f}, accC = {0.f, 0.f}, accD = {0.f, 0.f};
            DOT64(xc)
            po[2 * UDIM] = (accA + accB) + (accC + accD); }
        {   f32x2 accA = {br, bh}, accB = {0.f, 0.f}, accC = {0.f, 0.f}, accD = {0.f, 0.f};
            DOT64(xd)
            po[3 * UDIM] = (accA + accB) + (accC + accD); }

        xa = na; xb = nb; xc = nc; xd = nd;
    }
}

// ---------------- Kernel 2: recurrence ----------------
// 512 blocks x 256 = 2048 waves = exactly 2 waves/SIMD, 1 batch row/wave.
__global__ __launch_bounds__(256)
__attribute__((amdgpu_waves_per_eu(2, 2)))
void rec_kernel(
    const f32x2* __restrict__ pre,   // [B*T,64] {pre_r, pre_h}
    const float* __restrict__ att,   // [B,T]
    const float* __restrict__ h0,    // [B,64]
    const float* __restrict__ w_hr,  // [64,64]
    const float* __restrict__ w_hh,  // [64,64]
    const float* __restrict__ b_hh,  // [64]
    float* __restrict__ out)         // [B,T,64]
{
    const int u = threadIdx.x & 63;
    const int row = (int)((blockIdx.x * blockDim.x + threadIdx.x) >> 6);
    const float* pA = w_hr;
    const float* pB = w_hh;

    ALL64(DECLW)
    ALL64(LOADW)

    const float bg = b_hh[u];

    float h = h0[(long)row * UDIM + u];

    const f32x2* pp = pre + (long)row * T_STEPS * UDIM + u;
    const float* ap = att + (long)row * T_STEPS;
    float*       op = out + (long)row * T_STEPS * UDIM + u;

    // 3-deep prefetch pipeline (static shift registers)
    f32x2 pv0 = pp[0 * UDIM];
    f32x2 pv1 = pp[1 * UDIM];
    f32x2 pv2 = pp[2 * UDIM];
    float av0 = ap[0];
    float av1 = ap[1];
    float av2 = ap[2];

    for (int t = 0; t < T_STEPS; ++t) {
        PIN_LIVE

        const int tf = (t + 3 < T_STEPS) ? (t + 3) : (T_STEPS - 1);
        f32x2 pvn = pp[(long)tf * UDIM];
        float avn = ap[tf];

        f32x2 accA = {0.f, 0.f}, accB = {0.f, 0.f}, accC = {0.f, 0.f}, accD = {0.f, 0.f};
        DOT64(h)
        f32x2 s = (accA + accB) + (accC + accD);   // {h@w_hr, h@w_hh}

        const float r  = fast_sigmoid(pv0.x + s.x);
        const float hc = fast_tanh(fmaf(r, s.y + bg, pv0.y));
        h = fmaf(av0, hc - h, h);                  // (1-a)h + a*hc

        op[(long)t * UDIM] = h;

        pv0 = pv1; pv1 = pv2; pv2 = pvn;
        av0 = av1; av1 = av2; av2 = avn;
    }
}

// ---------------- Fallback: fused kernel (small ws) ----------------
__global__ __launch_bounds__(256) void agru_fused_kernel(
    const float* __restrict__ x, const float* __restrict__ att,
    const float* __restrict__ h0,
    const float* __restrict__ w_ir, const float* __restrict__ w_hr,
    const float* __restrict__ b_ir, const float* __restrict__ b_hr,
    const float* __restrict__ w_ih, const float* __restrict__ w_hh,
    const float* __restrict__ b_ih, const float* __restrict__ b_hh,
    float* __restrict__ out)
{
    __shared__ float lds[4 * UDIM * UDIM];
    const int tid = threadIdx.x;
    #pragma unroll
    for (int i = 0; i < 16; ++i) {
        int e = tid + 256 * i;
        lds[e] = w_ir[e]; lds[4096 + e] = w_ih[e];
        lds[8192 + e] = w_hr[e]; lds[12288 + e] = w_hh[e];
    }
    __syncthreads();

    const int wave = tid >> 6;
    const int u = tid & 63;
    const int r0 = blockIdx.x * 8 + wave * 2;
    const int r1 = r0 + 1;

    float h_0 = h0[r0 * UDIM + u];
    float h_1 = h0[r1 * UDIM + u];
    const float bR = b_ir[u] + b_hr[u];
    const float bH = b_ih[u];
    const float bG = b_hh[u];

    const float* xp0 = x + (long)r0 * T_STEPS * UDIM + u;
    const float* xp1 = x + (long)r1 * T_STEPS * UDIM + u;
    const float* ap0 = att + (long)r0 * T_STEPS;
    const float* ap1 = att + (long)r1 * T_STEPS;
    float* op0 = out + (long)r0 * T_STEPS * UDIM + u;
    float* op1 = out + (long)r1 * T_STEPS * UDIM + u;

    float xv0 = xp0[0], xv1 = xp1[0], a0 = ap0[0], a1 = ap1[0];

    for (int t = 0; t < T_STEPS; ++t) {
        const int tn = (t + 1 < T_STEPS) ? (t + 1) : t;
        float nxv0 = xp0[(long)tn * UDIM], nxv1 = xp1[(long)tn * UDIM];
        float na0 = ap0[tn], na1 = ap1[tn];

        float accR0 = bR, accR1 = bR, accH0 = bH, accH1 = bH, accG0 = bG, accG1 = bG;
        #pragma unroll
        for (int j = 0; j < 64; ++j) {
            const float wir = lds[j * 64 + u];
            const float wih = lds[4096 + j * 64 + u];
            const float whr = lds[8192 + j * 64 + u];
            const float whh = lds[12288 + j * 64 + u];
            const float xj0 = lane_bcast(xv0, j);
            const float xj1 = lane_bcast(xv1, j);
            const float hj0 = lane_bcast(h_0, j);
            const float hj1 = lane_bcast(h_1, j);
            accR0 = fmaf(xj0, wir, accR0); accR0 = fmaf(hj0, whr, accR0);
            accH0 = fmaf(xj0, wih, accH0); accG0 = fmaf(hj0, whh, accG0);
            accR1 = fmaf(xj1, wir, accR1); accR1 = fmaf(hj1, whr, accR1);
            accH1 = fmaf(xj1, wih, accH1); accG1 = fmaf(hj1, whh, accG1);
        }
        const float r0g = fast_sigmoid(accR0);
        const float r1g = fast_sigmoid(accR1);
        const float hc0 = fast_tanh(fmaf(r0g, accG0, accH0));
        const float hc1 = fast_tanh(fmaf(r1g, accG1, accH1));
        h_0 = fmaf(a0, hc0 - h_0, h_0);
        h_1 = fmaf(a1, hc1 - h_1, h_1);
        op0[(long)t * UDIM] = h_0;
        op1[(long)t * UDIM] = h_1;
        xv0 = nxv0; xv1 = nxv1; a0 = na0; a1 = na1;
    }
}

extern "C" void kernel_launch(void* const* d_in, const int* in_sizes, int n_in,
                              void* d_out, int out_size, void* d_ws, size_t ws_size,
                              hipStream_t stream) {
    (void)in_sizes; (void)n_in; (void)out_size;

    const float* x    = (const float*)d_in[0];
    const float* att  = (const float*)d_in[1];
    const float* h0   = (const float*)d_in[2];
    const float* w_ir = (const float*)d_in[3];
    const float* w_hr = (const float*)d_in[4];
    const float* b_ir = (const float*)d_in[5];
    const float* b_hr = (const float*)d_in[6];
    const float* w_ih = (const float*)d_in[7];
    const float* w_hh = (const float*)d_in[8];
    const float* b_ih = (const float*)d_in[9];
    const float* b_hh = (const float*)d_in[10];
    float* out = (float*)d_out;

    const size_t pre_bytes = (size_t)BATCH * T_STEPS * UDIM * sizeof(f32x2); // 210 MB

    if (ws_size >= pre_bytes) {
        f32x2* pre = (f32x2*)d_ws;
        proj_kernel<<<dim3(1024), dim3(256), 0, stream>>>(
            x, w_ir, w_ih, b_ir, b_hr, b_ih, pre);
        rec_kernel<<<dim3(512), dim3(256), 0, stream>>>(
            pre, att, h0, w_hr, w_hh, b_hh, out);
    } else {
        agru_fused_kernel<<<dim3(256), dim3(256), 0, stream>>>(
            x, att, h0, w_ir, w_hr, b_ir, b_hr, w_ih, w_hh, b_ih, b_hh, out);
    }
}